// Round 2
// baseline (1115.222 us; speedup 1.0000x reference)
//
#include <hip/hip_runtime.h>
#include <hip/hip_bf16.h>

typedef unsigned short u16;
typedef __bf16 bf16x8v __attribute__((ext_vector_type(8)));
typedef float f32x4v __attribute__((ext_vector_type(4)));

// ---------- bf16 helpers (RNE) ----------
__device__ __forceinline__ float bf2f(u16 u) {
    union { float f; unsigned int i; } c; c.i = ((unsigned int)u) << 16; return c.f;
}
__device__ __forceinline__ u16 f2bf(float f) {
    union { float f; unsigned int i; } c; c.f = f;
    unsigned int i = c.i;
    unsigned int lsb = (i >> 16) & 1u;
    i += 0x7fffu + lsb;
    return (u16)(i >> 16);
}

__device__ __forceinline__ void load_lds16(const void* g, void* l) {
    __builtin_amdgcn_global_load_lds(
        (const __attribute__((address_space(1))) void*)g,
        (__attribute__((address_space(3))) void*)l, 16, 0, 0);
}

// ---------- weight packing: Wt[n][k] = W[k][n], K padded with zeros ----------
__global__ void pack_w(const float* __restrict__ W, u16* __restrict__ Wt, int K, int Kpad) {
    int idx = blockIdx.x * 256 + threadIdx.x;       // over 256*Kpad
    if (idx >= 256 * Kpad) return;
    int n = idx / Kpad, k = idx % Kpad;
    float v = (k < K) ? W[k * 256 + n] : 0.f;
    Wt[idx] = f2bf(v);
}

// W_o packed for reordered concat: a_input = [a_message(256) | f_atoms(133) | pad(to 448)]
__global__ void pack_wo(const float* __restrict__ W_o, u16* __restrict__ Wt) {
    int idx = blockIdx.x * 256 + threadIdx.x;       // over 256*448
    if (idx >= 256 * 448) return;
    int n = idx / 448, k = idx % 448;
    float v;
    if (k < 256)       v = W_o[(133 + k) * 256 + n];   // a_message part
    else if (k < 389)  v = W_o[(k - 256) * 256 + n];   // f_atoms part
    else               v = 0.f;
    Wt[idx] = f2bf(v);
}

// ---------- f_bonds fp32[250000][147] -> bf16[250000][192] zero-padded ----------
__global__ void convert_fbonds(const float* __restrict__ fb, u16* __restrict__ out, int nB) {
    int idx = blockIdx.x * 256 + threadIdx.x;       // over nB*192
    if (idx >= nB * 192) return;
    int b = idx / 192, k = idx % 192;
    float v = (k < 147) ? fb[b * 147 + k] : 0.f;
    out[idx] = f2bf(v);
}

// ---------- f_atoms -> a_input cols 256..447 (bf16, zero pad 389..447) ----------
__global__ void pack_fatoms(const float* __restrict__ fa, u16* __restrict__ a_input, int nA) {
    int idx = blockIdx.x * 256 + threadIdx.x;       // over nA*192
    if (idx >= nA * 192) return;
    int a = idx / 192, c = idx % 192;
    float v = (c < 133) ? fa[a * 133 + c] : 0.f;
    a_input[(size_t)a * 448 + 256 + c] = f2bf(v);
}

// ---------- gather: amsg[a][h] = sum_j relu?(msg[a2b[a][j]][h]) * w_bonds[a2b[a][j]] ----------
// 64 lanes per atom, 4 cols/lane, 4 atoms per block
template <bool RELU>
__global__ __launch_bounds__(256)
void gather_kernel(const u16* __restrict__ msg, const int* __restrict__ a2b,
                   const float* __restrict__ w_bonds, u16* __restrict__ out,
                   int nAtoms, int ostride) {
    int t = threadIdx.x;
    int atom = blockIdx.x * 4 + (t >> 6);
    int lane = t & 63;
    if (atom >= nAtoms) return;
    float a0 = 0.f, a1 = 0.f, a2 = 0.f, a3 = 0.f;
#pragma unroll
    for (int j = 0; j < 6; ++j) {
        int b = a2b[atom * 6 + j];
        float w = w_bonds[b];
        uint2 v = *(const uint2*)(msg + (size_t)b * 256 + lane * 4);
        float m0 = bf2f((u16)(v.x & 0xffff));
        float m1 = bf2f((u16)(v.x >> 16));
        float m2 = bf2f((u16)(v.y & 0xffff));
        float m3 = bf2f((u16)(v.y >> 16));
        if (RELU) { m0 = fmaxf(m0, 0.f); m1 = fmaxf(m1, 0.f); m2 = fmaxf(m2, 0.f); m3 = fmaxf(m3, 0.f); }
        a0 += w * m0; a1 += w * m1; a2 += w * m2; a3 += w * m3;
    }
    uint2 o;
    o.x = (unsigned)f2bf(a0) | ((unsigned)f2bf(a1) << 16);
    o.y = (unsigned)f2bf(a2) | ((unsigned)f2bf(a3) << 16);
    *(uint2*)(out + (size_t)atom * ostride + lane * 4) = o;
}

// ---------- directed message: mdir[b][h] = amsg[b2a[b]][h] - relu?(msg[b2revb[b]][h]) ----------
template <bool RELU>
__global__ __launch_bounds__(256)
void direct_kernel(const u16* __restrict__ amsg, const u16* __restrict__ msg,
                   const int* __restrict__ b2a, const int* __restrict__ b2revb,
                   u16* __restrict__ mdir, int nBonds) {
    int t = threadIdx.x;
    int bond = blockIdx.x * 4 + (t >> 6);
    int lane = t & 63;
    if (bond >= nBonds) return;
    int sa = b2a[bond], rb = b2revb[bond];
    uint2 va = *(const uint2*)(amsg + (size_t)sa * 256 + lane * 4);
    uint2 vr = *(const uint2*)(msg + (size_t)rb * 256 + lane * 4);
    float m0 = bf2f((u16)(vr.x & 0xffff));
    float m1 = bf2f((u16)(vr.x >> 16));
    float m2 = bf2f((u16)(vr.y & 0xffff));
    float m3 = bf2f((u16)(vr.y >> 16));
    if (RELU) { m0 = fmaxf(m0, 0.f); m1 = fmaxf(m1, 0.f); m2 = fmaxf(m2, 0.f); m3 = fmaxf(m3, 0.f); }
    float r0 = bf2f((u16)(va.x & 0xffff)) - m0;
    float r1 = bf2f((u16)(va.x >> 16))    - m1;
    float r2 = bf2f((u16)(va.y & 0xffff)) - m2;
    float r3 = bf2f((u16)(va.y >> 16))    - m3;
    uint2 o;
    o.x = (unsigned)f2bf(r0) | ((unsigned)f2bf(r1) << 16);
    o.y = (unsigned)f2bf(r2) | ((unsigned)f2bf(r3) << 16);
    *(uint2*)(mdir + (size_t)bond * 256 + lane * 4) = o;
}

// ---------- GEMM: C[M][256] = A[M][Kpad] @ Bt[256][Kpad]^T, bf16 in, fp32 acc ----------
// BK=64: 128x128 block tile, 4 waves (2x2), each wave 64x64 via 4x4 16x16x32 MFMA tiles.
// MODE 0: out0=inp (bf16 acc, no activation)
// MODE 1: out0=msg = bf16(relu(bf2f(inp)+acc))
// MODE 2: outf = relu(acc + bias[col])  (fp32)
template <int MODE>
__global__ __launch_bounds__(256)
void gemm_kernel(const u16* __restrict__ A, const u16* __restrict__ Bt,
                 int M, int Kpad,
                 const u16* __restrict__ inp, const float* __restrict__ bias,
                 u16* __restrict__ out0, float* __restrict__ outf) {
    __shared__ u16 As[128 * 64];
    __shared__ u16 Bs[128 * 64];
    const int tid = threadIdx.x;
    const int wave = tid >> 6;
    const int lane = tid & 63;
    const int bm = blockIdx.x * 128;
    const int bn = blockIdx.y * 128;
    const int wr = wave >> 1, wc = wave & 1;
    const int srow = lane >> 3;   // 8 rows per global_load_lds inst (128 B/row)
    const int sseg = lane & 7;    // 16B segment within 128B row

    f32x4v acc[4][4];
#pragma unroll
    for (int i = 0; i < 4; ++i)
#pragma unroll
        for (int j = 0; j < 4; ++j) acc[i][j] = (f32x4v){0.f, 0.f, 0.f, 0.f};

    const int mrow = lane & 15, quad = lane >> 4;

    for (int k0 = 0; k0 < Kpad; k0 += 64) {
        __syncthreads();
#pragma unroll
        for (int s = 0; s < 4; ++s) {
            int rb = wave * 32 + s * 8;                   // wave-uniform LDS base row
            int ra = bm + rb + srow; if (ra >= M) ra = M - 1;
            load_lds16(A + (size_t)ra * Kpad + k0 + sseg * 8, &As[rb * 64]);
            int rn = bn + rb + srow;                      // always < 256
            load_lds16(Bt + (size_t)rn * Kpad + k0 + sseg * 8, &Bs[rb * 64]);
        }
        __syncthreads();
#pragma unroll
        for (int q = 0; q < 2; ++q) {
            bf16x8v a_frag[4], b_frag[4];
#pragma unroll
            for (int t = 0; t < 4; ++t) {
                a_frag[t] = *(const bf16x8v*)&As[(wr * 64 + t * 16 + mrow) * 64 + q * 32 + quad * 8];
                b_frag[t] = *(const bf16x8v*)&Bs[(wc * 64 + t * 16 + mrow) * 64 + q * 32 + quad * 8];
            }
#pragma unroll
            for (int ti = 0; ti < 4; ++ti)
#pragma unroll
                for (int tj = 0; tj < 4; ++tj)
                    acc[ti][tj] = __builtin_amdgcn_mfma_f32_16x16x32_bf16(
                        a_frag[ti], b_frag[tj], acc[ti][tj], 0, 0, 0);
        }
    }

    // epilogue: C/D layout col=lane&15, row=quad*4+reg
#pragma unroll
    for (int ti = 0; ti < 4; ++ti) {
#pragma unroll
        for (int r = 0; r < 4; ++r) {
            int grow = bm + wr * 64 + ti * 16 + quad * 4 + r;
            if (grow < M) {
#pragma unroll
                for (int tj = 0; tj < 4; ++tj) {
                    int gcol = bn + wc * 64 + tj * 16 + mrow;
                    size_t idx = (size_t)grow * 256 + gcol;
                    float v = acc[ti][tj][r];
                    if constexpr (MODE == 0) {
                        out0[idx] = f2bf(v);
                    } else if constexpr (MODE == 1) {
                        float s = bf2f(inp[idx]) + v;
                        out0[idx] = f2bf(s > 0.f ? s : 0.f);
                    } else {
                        float s = v + bias[gcol];
                        outf[idx] = s > 0.f ? s : 0.f;
                    }
                }
            }
        }
    }
}

// ---------- per-molecule weighted mean (mol_ids sorted) ----------
__global__ __launch_bounds__(256)
void aggregate_kernel(const float* __restrict__ hid, const float* __restrict__ w_atoms,
                      const int* __restrict__ mol_ids, const float* __restrict__ deg,
                      float* __restrict__ out, int nAtoms) {
    int m = blockIdx.x;
    int t = threadIdx.x;
    int lo = 0, hi = nAtoms;
    while (lo < hi) { int mid = (lo + hi) >> 1; if (mol_ids[mid] < m) lo = mid + 1; else hi = mid; }
    int start = lo;
    lo = start; hi = nAtoms;
    while (lo < hi) { int mid = (lo + hi) >> 1; if (mol_ids[mid] < m + 1) lo = mid + 1; else hi = mid; }
    int end = lo;
    float acc = 0.f, wsum = 0.f;
    for (int a = start; a < end; ++a) {
        float w = w_atoms[a];
        wsum += w;
        acc += w * hid[(size_t)a * 256 + t];
    }
    float res = (wsum > 0.f) ? deg[m] * acc / wsum : 0.f;
    out[m * 256 + t] = res;
}

// ---------- launch ----------
extern "C" void kernel_launch(void* const* d_in, const int* in_sizes, int n_in,
                              void* d_out, int out_size, void* d_ws, size_t ws_size,
                              hipStream_t stream) {
    const float* f_atoms = (const float*)d_in[0];
    const float* f_bonds = (const float*)d_in[1];
    const float* w_atoms = (const float*)d_in[2];
    const float* w_bonds = (const float*)d_in[3];
    const float* W_i     = (const float*)d_in[4];
    const float* W_h     = (const float*)d_in[5];
    const float* W_o     = (const float*)d_in[6];
    const float* b_o     = (const float*)d_in[7];
    const float* deg     = (const float*)d_in[8];
    const int*   a2b     = (const int*)d_in[9];
    const int*   b2a     = (const int*)d_in[10];
    const int*   b2revb  = (const int*)d_in[11];
    const int*   mol_ids = (const int*)d_in[12];
    float* out = (float*)d_out;

    const int nB = 250000, nA = 100000, nM = 2000;

    // ws layout (bytes):
    //  P0 @ 0         : inp bf16 [250000][256] = 128,000,000  (later: hid fp32 100000*256*4 = 102,400,000)
    //  P1 @ 128M      : msg bf16 [250000][256] = 128,000,000
    //  P2 @ 256M      : f_bonds_bf [250000][192] (96MB) / mdir [250000][256] (128MB) / a_input [100000][448] (89.6MB)
    //  P3 @ 384M      : amsg bf16 [100000][256] = 51,200,000
    //  P4 @ 435.2M    : Wt_i (98,304) | Wt_h (131,072) | Wt_o (229,376)
    char* ws = (char*)d_ws;
    u16* inp    = (u16*)(ws);
    u16* msg    = (u16*)(ws + 128000000L);
    u16* buf2   = (u16*)(ws + 256000000L);
    u16* amsg   = (u16*)(ws + 384000000L);
    u16* wt_i   = (u16*)(ws + 435200000L);
    u16* wt_h   = (u16*)(ws + 435200000L + 98304L);
    u16* wt_o   = (u16*)(ws + 435200000L + 98304L + 131072L);
    float* hid  = (float*)(ws);  // aliases inp (dead by GEMM3)

    if (ws_size < 435658752UL) return;  // insufficient workspace

    dim3 blk(256);
    pack_w<<<dim3((256 * 192 + 255) / 256), blk, 0, stream>>>(W_i, wt_i, 147, 192);
    pack_w<<<dim3((256 * 256 + 255) / 256), blk, 0, stream>>>(W_h, wt_h, 256, 256);
    pack_wo<<<dim3((256 * 448 + 255) / 256), blk, 0, stream>>>(W_o, wt_o);
    convert_fbonds<<<dim3(nB * 192 / 256), blk, 0, stream>>>(f_bonds, buf2, nB);

    // input layer: inp = f_bonds @ W_i  (msg = relu(inp) applied on the fly downstream)
    gemm_kernel<0><<<dim3((nB + 127) / 128, 2), blk, 0, stream>>>(
        buf2, wt_i, nB, 192, nullptr, nullptr, inp, nullptr);

    // iteration 0: msg == relu(inp), read inp with RELU flag
    gather_kernel<true><<<dim3(nA / 4), blk, 0, stream>>>(inp, a2b, w_bonds, amsg, nA, 256);
    direct_kernel<true><<<dim3(nB / 4), blk, 0, stream>>>(amsg, inp, b2a, b2revb, buf2, nB);
    gemm_kernel<1><<<dim3((nB + 127) / 128, 2), blk, 0, stream>>>(
        buf2, wt_h, nB, 256, inp, nullptr, msg, nullptr);

    // iteration 1: msg materialized
    gather_kernel<false><<<dim3(nA / 4), blk, 0, stream>>>(msg, a2b, w_bonds, amsg, nA, 256);
    direct_kernel<false><<<dim3(nB / 4), blk, 0, stream>>>(amsg, msg, b2a, b2revb, buf2, nB);
    gemm_kernel<1><<<dim3((nB + 127) / 128, 2), blk, 0, stream>>>(
        buf2, wt_h, nB, 256, inp, nullptr, msg, nullptr);

    // final readout: a_input = [final gather | f_atoms | 0] ; hid = relu(a_input @ W_o + b_o)
    pack_fatoms<<<dim3(nA * 192 / 256), blk, 0, stream>>>(f_atoms, buf2, nA);
    gather_kernel<false><<<dim3(nA / 4), blk, 0, stream>>>(msg, a2b, w_bonds, buf2, nA, 448);
    gemm_kernel<2><<<dim3((nA + 127) / 128, 2), blk, 0, stream>>>(
        buf2, wt_o, nA, 448, nullptr, b_o, nullptr, hid);

    aggregate_kernel<<<dim3(nM), blk, 0, stream>>>(hid, w_atoms, mol_ids, deg, out, nA);
}

// Round 3
// 1082.837 us; speedup vs baseline: 1.0299x; 1.0299x over previous
//
#include <hip/hip_runtime.h>
#include <hip/hip_bf16.h>

typedef unsigned short u16;
typedef __bf16 bf16x8v __attribute__((ext_vector_type(8)));
typedef float f32x4v __attribute__((ext_vector_type(4)));

// ---------- bf16 helpers (RNE) ----------
__device__ __forceinline__ float bf2f(u16 u) {
    union { float f; unsigned int i; } c; c.i = ((unsigned int)u) << 16; return c.f;
}
__device__ __forceinline__ u16 f2bf(float f) {
    union { float f; unsigned int i; } c; c.f = f;
    unsigned int i = c.i;
    unsigned int lsb = (i >> 16) & 1u;
    i += 0x7fffu + lsb;
    return (u16)(i >> 16);
}

// ---------- weight packing: Wt[n][k] = W[k][n], K padded with zeros ----------
__global__ void pack_w(const float* __restrict__ W, u16* __restrict__ Wt, int K, int Kpad) {
    int idx = blockIdx.x * 256 + threadIdx.x;       // over 256*Kpad
    if (idx >= 256 * Kpad) return;
    int n = idx / Kpad, k = idx % Kpad;
    float v = (k < K) ? W[k * 256 + n] : 0.f;
    Wt[idx] = f2bf(v);
}

// W_o packed for reordered concat: a_input = [a_message(256) | f_atoms(133) | pad(to 448)]
__global__ void pack_wo(const float* __restrict__ W_o, u16* __restrict__ Wt) {
    int idx = blockIdx.x * 256 + threadIdx.x;       // over 256*448
    if (idx >= 256 * 448) return;
    int n = idx / 448, k = idx % 448;
    float v;
    if (k < 256)       v = W_o[(133 + k) * 256 + n];   // a_message part
    else if (k < 389)  v = W_o[(k - 256) * 256 + n];   // f_atoms part
    else               v = 0.f;
    Wt[idx] = f2bf(v);
}

// ---------- f_bonds fp32[250000][147] -> bf16[250000][192] zero-padded ----------
__global__ void convert_fbonds(const float* __restrict__ fb, u16* __restrict__ out, int nB) {
    int idx = blockIdx.x * 256 + threadIdx.x;       // over nB*192
    if (idx >= nB * 192) return;
    int b = idx / 192, k = idx % 192;
    float v = (k < 147) ? fb[b * 147 + k] : 0.f;
    out[idx] = f2bf(v);
}

// ---------- f_atoms -> a_input cols 256..447 (bf16, zero pad 389..447) ----------
__global__ void pack_fatoms(const float* __restrict__ fa, u16* __restrict__ a_input, int nA) {
    int idx = blockIdx.x * 256 + threadIdx.x;       // over nA*192
    if (idx >= nA * 192) return;
    int a = idx / 192, c = idx % 192;
    float v = (c < 133) ? fa[a * 133 + c] : 0.f;
    a_input[(size_t)a * 448 + 256 + c] = f2bf(v);
}

// ---------- gather: amsg[a][h] = sum_j relu?(msg[a2b[a][j]][h]) * w_bonds[a2b[a][j]] ----------
template <bool RELU>
__global__ __launch_bounds__(256)
void gather_kernel(const u16* __restrict__ msg, const int* __restrict__ a2b,
                   const float* __restrict__ w_bonds, u16* __restrict__ out,
                   int nAtoms, int ostride) {
    int t = threadIdx.x;
    int atom = blockIdx.x * 4 + (t >> 6);
    int lane = t & 63;
    if (atom >= nAtoms) return;
    float a0 = 0.f, a1 = 0.f, a2 = 0.f, a3 = 0.f;
#pragma unroll
    for (int j = 0; j < 6; ++j) {
        int b = a2b[atom * 6 + j];
        float w = w_bonds[b];
        uint2 v = *(const uint2*)(msg + (size_t)b * 256 + lane * 4);
        float m0 = bf2f((u16)(v.x & 0xffff));
        float m1 = bf2f((u16)(v.x >> 16));
        float m2 = bf2f((u16)(v.y & 0xffff));
        float m3 = bf2f((u16)(v.y >> 16));
        if (RELU) { m0 = fmaxf(m0, 0.f); m1 = fmaxf(m1, 0.f); m2 = fmaxf(m2, 0.f); m3 = fmaxf(m3, 0.f); }
        a0 += w * m0; a1 += w * m1; a2 += w * m2; a3 += w * m3;
    }
    uint2 o;
    o.x = (unsigned)f2bf(a0) | ((unsigned)f2bf(a1) << 16);
    o.y = (unsigned)f2bf(a2) | ((unsigned)f2bf(a3) << 16);
    *(uint2*)(out + (size_t)atom * ostride + lane * 4) = o;
}

// ---------- directed message: mdir[b][h] = amsg[b2a[b]][h] - relu?(msg[b2revb[b]][h]) ----------
template <bool RELU>
__global__ __launch_bounds__(256)
void direct_kernel(const u16* __restrict__ amsg, const u16* __restrict__ msg,
                   const int* __restrict__ b2a, const int* __restrict__ b2revb,
                   u16* __restrict__ mdir, int nBonds) {
    int t = threadIdx.x;
    int bond = blockIdx.x * 4 + (t >> 6);
    int lane = t & 63;
    if (bond >= nBonds) return;
    int sa = b2a[bond], rb = b2revb[bond];
    uint2 va = *(const uint2*)(amsg + (size_t)sa * 256 + lane * 4);
    uint2 vr = *(const uint2*)(msg + (size_t)rb * 256 + lane * 4);
    float m0 = bf2f((u16)(vr.x & 0xffff));
    float m1 = bf2f((u16)(vr.x >> 16));
    float m2 = bf2f((u16)(vr.y & 0xffff));
    float m3 = bf2f((u16)(vr.y >> 16));
    if (RELU) { m0 = fmaxf(m0, 0.f); m1 = fmaxf(m1, 0.f); m2 = fmaxf(m2, 0.f); m3 = fmaxf(m3, 0.f); }
    float r0 = bf2f((u16)(va.x & 0xffff)) - m0;
    float r1 = bf2f((u16)(va.x >> 16))    - m1;
    float r2 = bf2f((u16)(va.y & 0xffff)) - m2;
    float r3 = bf2f((u16)(va.y >> 16))    - m3;
    uint2 o;
    o.x = (unsigned)f2bf(r0) | ((unsigned)f2bf(r1) << 16);
    o.y = (unsigned)f2bf(r2) | ((unsigned)f2bf(r3) << 16);
    *(uint2*)(mdir + (size_t)bond * 256 + lane * 4) = o;
}

// ---------- resident-weight streaming GEMM ----------
// C[M][256] slice: A[M][KPAD] @ Bt[256][KPAD]^T for columns [blockIdx.y*NT*16, +NT*16)
// Weight slice staged in LDS once (row-padded +8 elems -> 2-way bank aliasing, free).
// A streamed global->register fragments (lane layout A[m=lane&15][k=quad*8+j], 16B/lane).
// NO barriers in the steady-state loop. Block = 4 waves stacked in M (256 rows/chunk),
// wave tile = 64 x (NT*16). Grid-stride over M chunks.
// MODE 0: out0 = bf16(acc)
// MODE 1: out0 = bf16(relu(bf2f(inp)+acc))
// MODE 2: outf = relu(acc + bias[col]) (fp32)
template <int MODE, int KPAD, int NT>
__global__ __launch_bounds__(256, 2)
void gemm_rw(const u16* __restrict__ A, const u16* __restrict__ Bt, int M,
             const u16* __restrict__ inp, const float* __restrict__ bias,
             u16* __restrict__ out0, float* __restrict__ outf) {
    constexpr int LSTR = KPAD + 8;      // LDS row stride (elems): +16B keeps b128 align
    constexpr int NROWS = NT * 16;
    __shared__ u16 Bs[NROWS * LSTR];
    const int tid = threadIdx.x;
    const int wave = tid >> 6;
    const int lane = tid & 63;
    const int mrow = lane & 15;
    const int quad = lane >> 4;
    const int nbase = blockIdx.y * NROWS;

    // ---- stage weight slice once ----
    constexpr int KC = KPAD / 8;        // 16B chunks per row
    for (int i = tid; i < NROWS * KC; i += 256) {
        int r = i / KC, kc = i % KC;
        *(uint4*)&Bs[r * LSTR + kc * 8] =
            *(const uint4*)&Bt[(size_t)(nbase + r) * KPAD + kc * 8];
    }
    __syncthreads();

    for (long chunk = blockIdx.x; chunk * 256 < (long)M; chunk += gridDim.x) {
        const long mbase = chunk * 256 + wave * 64;
        // per-m-tile A element offsets (row-clamped)
        long aoff[4];
#pragma unroll
        for (int t = 0; t < 4; ++t) {
            long r = mbase + t * 16 + mrow;
            if (r >= M) r = M - 1;
            aoff[t] = r * KPAD + quad * 8;
        }

        f32x4v acc[4][NT];
#pragma unroll
        for (int t = 0; t < 4; ++t)
#pragma unroll
            for (int j = 0; j < NT; ++j) acc[t][j] = (f32x4v){0.f, 0.f, 0.f, 0.f};

#pragma unroll 2
        for (int k0 = 0; k0 < KPAD; k0 += 32) {
            bf16x8v a_frag[4], b_frag[NT];
#pragma unroll
            for (int t = 0; t < 4; ++t)
                a_frag[t] = *(const bf16x8v*)&A[aoff[t] + k0];
#pragma unroll
            for (int j = 0; j < NT; ++j)
                b_frag[j] = *(const bf16x8v*)&Bs[(j * 16 + mrow) * LSTR + k0 + quad * 8];
#pragma unroll
            for (int t = 0; t < 4; ++t)
#pragma unroll
                for (int j = 0; j < NT; ++j)
                    acc[t][j] = __builtin_amdgcn_mfma_f32_16x16x32_bf16(
                        a_frag[t], b_frag[j], acc[t][j], 0, 0, 0);
        }

        // epilogue: C/D layout col=lane&15, row=quad*4+reg
#pragma unroll
        for (int t = 0; t < 4; ++t) {
#pragma unroll
            for (int r = 0; r < 4; ++r) {
                long grow = mbase + t * 16 + quad * 4 + r;
                if (grow < M) {
#pragma unroll
                    for (int j = 0; j < NT; ++j) {
                        int gcol = nbase + j * 16 + mrow;
                        size_t idx = (size_t)grow * 256 + gcol;
                        float v = acc[t][j][r];
                        if constexpr (MODE == 0) {
                            out0[idx] = f2bf(v);
                        } else if constexpr (MODE == 1) {
                            float s = bf2f(inp[idx]) + v;
                            out0[idx] = f2bf(s > 0.f ? s : 0.f);
                        } else {
                            float s = v + bias[gcol];
                            outf[idx] = s > 0.f ? s : 0.f;
                        }
                    }
                }
            }
        }
    }
}

// ---------- per-molecule weighted mean (mol_ids sorted) ----------
__global__ __launch_bounds__(256)
void aggregate_kernel(const float* __restrict__ hid, const float* __restrict__ w_atoms,
                      const int* __restrict__ mol_ids, const float* __restrict__ deg,
                      float* __restrict__ out, int nAtoms) {
    int m = blockIdx.x;
    int t = threadIdx.x;
    int lo = 0, hi = nAtoms;
    while (lo < hi) { int mid = (lo + hi) >> 1; if (mol_ids[mid] < m) lo = mid + 1; else hi = mid; }
    int start = lo;
    lo = start; hi = nAtoms;
    while (lo < hi) { int mid = (lo + hi) >> 1; if (mol_ids[mid] < m + 1) lo = mid + 1; else hi = mid; }
    int end = lo;
    float acc = 0.f, wsum = 0.f;
    for (int a = start; a < end; ++a) {
        float w = w_atoms[a];
        wsum += w;
        acc += w * hid[(size_t)a * 256 + t];
    }
    float res = (wsum > 0.f) ? deg[m] * acc / wsum : 0.f;
    out[m * 256 + t] = res;
}

// ---------- launch ----------
extern "C" void kernel_launch(void* const* d_in, const int* in_sizes, int n_in,
                              void* d_out, int out_size, void* d_ws, size_t ws_size,
                              hipStream_t stream) {
    const float* f_atoms = (const float*)d_in[0];
    const float* f_bonds = (const float*)d_in[1];
    const float* w_atoms = (const float*)d_in[2];
    const float* w_bonds = (const float*)d_in[3];
    const float* W_i     = (const float*)d_in[4];
    const float* W_h     = (const float*)d_in[5];
    const float* W_o     = (const float*)d_in[6];
    const float* b_o     = (const float*)d_in[7];
    const float* deg     = (const float*)d_in[8];
    const int*   a2b     = (const int*)d_in[9];
    const int*   b2a     = (const int*)d_in[10];
    const int*   b2revb  = (const int*)d_in[11];
    const int*   mol_ids = (const int*)d_in[12];
    float* out = (float*)d_out;

    const int nB = 250000, nA = 100000, nM = 2000;

    // ws layout (bytes):
    //  P0 @ 0         : inp bf16 [250000][256] = 128,000,000  (later: hid fp32 100000*256*4)
    //  P1 @ 128M      : msg bf16 [250000][256] = 128,000,000
    //  P2 @ 256M      : f_bonds_bf [250000][192] / mdir [250000][256] / a_input [100000][448]
    //  P3 @ 384M      : amsg bf16 [100000][256] = 51,200,000
    //  P4 @ 435.2M    : Wt_i (98,304) | Wt_h (131,072) | Wt_o (229,376)
    char* ws = (char*)d_ws;
    u16* inp    = (u16*)(ws);
    u16* msg    = (u16*)(ws + 128000000L);
    u16* buf2   = (u16*)(ws + 256000000L);
    u16* amsg   = (u16*)(ws + 384000000L);
    u16* wt_i   = (u16*)(ws + 435200000L);
    u16* wt_h   = (u16*)(ws + 435200000L + 98304L);
    u16* wt_o   = (u16*)(ws + 435200000L + 98304L + 131072L);
    float* hid  = (float*)(ws);  // aliases inp (dead by GEMM3)

    if (ws_size < 435658752UL) return;  // insufficient workspace

    dim3 blk(256);
    pack_w<<<dim3((256 * 192 + 255) / 256), blk, 0, stream>>>(W_i, wt_i, 147, 192);
    pack_w<<<dim3((256 * 256 + 255) / 256), blk, 0, stream>>>(W_h, wt_h, 256, 256);
    pack_wo<<<dim3((256 * 448 + 255) / 256), blk, 0, stream>>>(W_o, wt_o);
    convert_fbonds<<<dim3(nB * 192 / 256), blk, 0, stream>>>(f_bonds, buf2, nB);

    // input layer: inp = f_bonds @ W_i  (msg = relu(inp) applied on the fly downstream)
    gemm_rw<0, 192, 8><<<dim3(512, 2), blk, 0, stream>>>(
        buf2, wt_i, nB, nullptr, nullptr, inp, nullptr);

    // iteration 0: msg == relu(inp), read inp with RELU flag
    gather_kernel<true><<<dim3(nA / 4), blk, 0, stream>>>(inp, a2b, w_bonds, amsg, nA, 256);
    direct_kernel<true><<<dim3(nB / 4), blk, 0, stream>>>(amsg, inp, b2a, b2revb, buf2, nB);
    gemm_rw<1, 256, 8><<<dim3(512, 2), blk, 0, stream>>>(
        buf2, wt_h, nB, inp, nullptr, msg, nullptr);

    // iteration 1: msg materialized
    gather_kernel<false><<<dim3(nA / 4), blk, 0, stream>>>(msg, a2b, w_bonds, amsg, nA, 256);
    direct_kernel<false><<<dim3(nB / 4), blk, 0, stream>>>(amsg, msg, b2a, b2revb, buf2, nB);
    gemm_rw<1, 256, 8><<<dim3(512, 2), blk, 0, stream>>>(
        buf2, wt_h, nB, inp, nullptr, msg, nullptr);

    // final readout: a_input = [final gather | f_atoms | 0] ; hid = relu(a_input @ W_o + b_o)
    pack_fatoms<<<dim3(nA * 192 / 256), blk, 0, stream>>>(f_atoms, buf2, nA);
    gather_kernel<false><<<dim3(nA / 4), blk, 0, stream>>>(msg, a2b, w_bonds, buf2, nA, 448);
    gemm_rw<2, 448, 4><<<dim3(256, 4), blk, 0, stream>>>(
        buf2, wt_o, nA, nullptr, b_o, nullptr, hid);

    aggregate_kernel<<<dim3(nM), blk, 0, stream>>>(hid, w_atoms, mol_ids, deg, out, nA);
}